// Round 6
// baseline (1178.127 us; speedup 1.0000x reference)
//
#include <hip/hip_runtime.h>
#include <stdint.h>

#define N_NODES 50000
#define HIDDEN  512
#define N_EDGES 200000

#define BK 32
#define LDP 40   // padded LDS row stride (k_gemm_w only)
#define NBX ((N_NODES + 127) / 128)

typedef __attribute__((ext_vector_type(8)))  short short8;
typedef __attribute__((ext_vector_type(4)))  float floatx4;
typedef __attribute__((ext_vector_type(16))) float floatx16;

__device__ inline float bf2f(ushort u) {
    union { uint32_t u; float f; } v; v.u = ((uint32_t)u) << 16; return v.f;
}
__device__ inline ushort f2bf(float f) {
    union { float f; uint32_t u; } v; v.f = f;
    uint32_t r = v.u + 0x7fffu + ((v.u >> 16) & 1u);   // round-to-nearest-even
    return (ushort)(r >> 16);
}
__device__ inline floatx4 mfma16(short8 a, short8 b, floatx4 c) {
    return __builtin_amdgcn_mfma_f32_16x16x32_bf16(a, b, c, 0, 0, 0);
}
__device__ inline floatx16 mfma32(short8 a, short8 b, floatx16 c) {
    return __builtin_amdgcn_mfma_f32_32x32x16_bf16(a, b, c, 0, 0, 0);
}
// inputs is arange(N_NODES); if harness kept int64, the int32 view is [0,0,1,0,2,0,...]
__device__ inline bool idx_is64(const int* __restrict__ inputs) {
    return inputs[1] == 0 && inputs[2] == 1;
}

// x = bf16(emb[inputs]) : 8 f32 -> 8 bf16 per thread
__global__ void k_gather(const int* __restrict__ inputs, const float* __restrict__ emb,
                         ushort* __restrict__ xb) {
    bool is64 = idx_is64(inputs);
    int t = blockIdx.x * blockDim.x + threadIdx.x;   // N_NODES*64 threads
    int row = t >> 6, s8 = (t & 63) << 3;
    if (row >= N_NODES) return;
    int srow = is64 ? inputs[2 * row] : inputs[row];
    srow = srow < 0 ? 0 : (srow >= N_NODES ? N_NODES - 1 : srow);
    const float* src = emb + (size_t)srow * HIDDEN + s8;
    float4 v0 = *(const float4*)(src);
    float4 v1 = *(const float4*)(src + 4);
    ushort o[8] = { f2bf(v0.x), f2bf(v0.y), f2bf(v0.z), f2bf(v0.w),
                    f2bf(v1.x), f2bf(v1.y), f2bf(v1.z), f2bf(v1.w) };
    *(uint4*)(xb + (size_t)row * HIDDEN + s8) = *(uint4*)o;
}

// generic f32 -> bf16 (8/thread), row-major preserved
__global__ void k_cvt8(const float* __restrict__ src, ushort* __restrict__ dst, int n) {
    int t = blockIdx.x * blockDim.x + threadIdx.x;
    int base = t * 8;
    if (base >= n) return;
    float4 v0 = *(const float4*)(src + base);
    float4 v1 = *(const float4*)(src + base + 4);
    ushort o[8] = { f2bf(v0.x), f2bf(v0.y), f2bf(v0.z), f2bf(v0.w),
                    f2bf(v1.x), f2bf(v1.y), f2bf(v1.z), f2bf(v1.w) };
    *(uint4*)(dst + base) = *(uint4*)o;
}

// Fragment-major weight layout for mfma_32x32x16_bf16 B operand:
// element (grow in [0,1536), k in [0,512)):
//   g = grow>>9, col = grow&511, cb = col>>5, lanelo = col&31,
//   kk = k>>4, hi = (k>>3)&1, j = k&7, lane = lanelo + hi*32
//   idx = (((g*16 + cb)*32 + kk)*64 + lane)*8 + j
// -> each (g,cb,kk) frag is a contiguous 1KB panel; wave load = base + lane*16.
__device__ inline size_t wf_index(int grow, int k) {
    int g3 = grow >> 9, gcol = grow & 511;
    int cb = gcol >> 5, llo = gcol & 31;
    int kk = k >> 4, hi = (k >> 3) & 1, jj = k & 7;
    return ((((size_t)g3 * 16 + cb) * 32 + kk) * 64 + llo + hi * 32) * 8 + jj;
}

// Wc[l][g][k] = sum_j wih[g][j] * W[l][k][j]  (combined gi weights), written frag-major.
// A = WihB [1536][512] contig-j ; B = Wb[l] [512][512] contig-j ; M=1536,N=512,K=512.
__global__ __launch_bounds__(256) void k_gemm_w(const ushort* __restrict__ Aw,
                                                const ushort* __restrict__ Bw,
                                                ushort* __restrict__ Cw) {
    __shared__ ushort As[128][LDP];
    __shared__ ushort Bs[128][LDP];
    const int l = blockIdx.z;
    const ushort* Bp = Bw + (size_t)l * HIDDEN * HIDDEN;
    ushort* Cp = Cw + (size_t)l * 3 * HIDDEN * HIDDEN;
    const int n0 = blockIdx.x * 128, c0 = blockIdx.y * 128;
    const int t = threadIdx.x;
    const int wave = t >> 6, lane = t & 63;
    const int wm = (wave >> 1) << 6, wn = (wave & 1) << 6;
    const int fr = lane & 15, fk = (lane >> 4) << 3;
    const int lm = t >> 2, lk = (t & 3) << 3;
    floatx4 acc[4][4] = {};

    for (int k0 = 0; k0 < HIDDEN; k0 += BK) {
        *(uint4*)&As[lm][lk]      = *(const uint4*)(Aw + (size_t)(n0 + lm) * HIDDEN + k0 + lk);
        *(uint4*)&As[64 + lm][lk] = *(const uint4*)(Aw + (size_t)(n0 + 64 + lm) * HIDDEN + k0 + lk);
        *(uint4*)&Bs[lm][lk]      = *(const uint4*)(Bp + (size_t)(c0 + lm) * HIDDEN + k0 + lk);
        *(uint4*)&Bs[64 + lm][lk] = *(const uint4*)(Bp + (size_t)(c0 + 64 + lm) * HIDDEN + k0 + lk);
        __syncthreads();
        short8 aa[4], bb[4];
        #pragma unroll
        for (int i = 0; i < 4; ++i) {
            aa[i] = *(const short8*)&As[wm + i * 16 + fr][fk];
            bb[i] = *(const short8*)&Bs[wn + i * 16 + fr][fk];
        }
        #pragma unroll
        for (int i = 0; i < 4; ++i)
            #pragma unroll
            for (int j = 0; j < 4; ++j)
                acc[i][j] = mfma16(aa[i], bb[j], acc[i][j]);
        __syncthreads();
    }
    const int er = (lane >> 4) << 2, ec = lane & 15;
    #pragma unroll
    for (int i = 0; i < 4; ++i)
        #pragma unroll
        for (int j = 0; j < 4; ++j)
            #pragma unroll
            for (int r = 0; r < 4; ++r) {
                int grow = n0 + wm + i * 16 + er + r;   // gi-output row (gate dim)
                int kcol = c0 + wn + j * 16 + ec;       // k dim
                Cp[wf_index(grow, kcol)] = f2bf(acc[i][j][r]);
            }
}

// pack w_hh (f32 [1536][512]) into fragment-major bf16
__global__ void k_pack_hh(const float* __restrict__ whh, ushort* __restrict__ wfh) {
    int t = blockIdx.x * blockDim.x + threadIdx.x;   // 1536*64 threads
    if (t >= 3 * HIDDEN * HIDDEN / 8) return;
    int grow = t >> 6, k = (t & 63) << 3;
    const float* src = whh + (size_t)grow * HIDDEN + k;
    ushort o[8];
    #pragma unroll
    for (int j = 0; j < 8; ++j) o[j] = f2bf(src[j]);
    *(uint4*)(wfh + wf_index(grow, k)) = *(uint4*)o;   // j=0..7 contiguous -> 16B store
}

// ---- counting sort of edges by dst (once per call; graph shared by both layers) ----
__global__ void k_hist(const int* __restrict__ inputs, const int* __restrict__ A,
                       int* __restrict__ count) {
    bool is64 = idx_is64(inputs);
    int e = blockIdx.x * blockDim.x + threadIdx.x;
    if (e >= N_EDGES) return;
    int d = is64 ? A[2 * (N_EDGES + e)] : A[N_EDGES + e];
    if (d < 0 || d >= N_NODES) return;
    atomicAdd(count + d, 1);
}

#define SCAN_T 1024
__global__ __launch_bounds__(SCAN_T) void k_scan(const int* __restrict__ count,
                                                 int* __restrict__ row_start,
                                                 int* __restrict__ cursor) {
    __shared__ int part[SCAN_T];
    const int t = threadIdx.x;
    const int chunk = (N_NODES + SCAN_T - 1) / SCAN_T;   // 49
    const int base = t * chunk;
    int s = 0;
    for (int i = 0; i < chunk; ++i) {
        int idx = base + i;
        if (idx < N_NODES) s += count[idx];
    }
    part[t] = s;
    __syncthreads();
    for (int off = 1; off < SCAN_T; off <<= 1) {
        int add = (t >= off) ? part[t - off] : 0;
        __syncthreads();
        part[t] += add;
        __syncthreads();
    }
    int running = (t == 0) ? 0 : part[t - 1];
    for (int i = 0; i < chunk; ++i) {
        int idx = base + i;
        if (idx < N_NODES) {
            row_start[idx] = running;
            cursor[idx] = running;
            running += count[idx];
        }
    }
    if (t == 0) row_start[N_NODES] = part[SCAN_T - 1];
}

__global__ void k_place(const int* __restrict__ inputs, const int* __restrict__ A,
                        int* __restrict__ cursor, int* __restrict__ esrc) {
    bool is64 = idx_is64(inputs);
    int e = blockIdx.x * blockDim.x + threadIdx.x;
    if (e >= N_EDGES) return;
    int s, d;
    if (is64) { s = A[2 * e]; d = A[2 * (N_EDGES + e)]; }
    else      { s = A[e];     d = A[N_EDGES + e]; }
    if (s < 0 || s >= N_NODES || d < 0 || d >= N_NODES) return;
    int pos = atomicAdd(cursor + d, 1);
    esrc[pos] = s;
}

// ax[n] = sum_{e: dst=n} x[src[e]] : one wave per node, lane owns 8 cols, f32 acc -> bf16
__global__ __launch_bounds__(256) void k_agg(const int* __restrict__ row_start,
                                             const int* __restrict__ esrc,
                                             const ushort* __restrict__ x,
                                             ushort* __restrict__ ax) {
    int node = blockIdx.x * 4 + (threadIdx.x >> 6);
    if (node >= N_NODES) return;
    int lane = threadIdx.x & 63;
    int q = lane << 3;
    int beg = row_start[node], end = row_start[node + 1];
    float acc[8] = {};
    for (int i = beg; i < end; ++i) {
        int s = esrc[i];
        uint4 v = *(const uint4*)(x + (size_t)s * HIDDEN + q);
        const ushort* u = (const ushort*)&v;
        #pragma unroll
        for (int j = 0; j < 8; ++j) acc[j] += bf2f(u[j]);
    }
    ushort o[8];
    #pragma unroll
    for (int j = 0; j < 8; ++j) o[j] = f2bf(acc[j]);
    *(uint4*)(ax + (size_t)node * HIDDEN + q) = *(uint4*)o;
}

// Fused GRU v7: pure-register GEMM -- NO LDS, NO barriers, NO DMA.
// v5/v6 post-mortem: at 2 waves/SIMD in barrier lockstep, every structure variant
// (serial drain, dbuf, counted vmcnt) lands 4-5x off the pipe floors -- the sync
// layer itself is the bottleneck. Removing it: the mfma32 A-operand is row-major-
// friendly (lane l holds 8 contiguous k-elems of row l&31 -> one 16B load from the
// activation row), and weights are frag-major (16B/lane coalesced). So each wave
// free-runs: per kk load 4 act frags (row-stride 1KB; the step's 4 loads consume
// whole 64B lines, L1/L2-absorbed; row panel is XCD-L2-hot from the dispatch map)
// + 6 weight frags (L1-shared within the block), then 12 mfma32. The compiler
// software-pipelines reg-dest loads well (m97 evidence); no vmcnt entanglement
// because there is no DMA. Block = 4 waves 2x2 (64rx32c each) for L1 sharing only.
template<bool F32OUT>
__global__ __launch_bounds__(256, 2) void k_gru7(
    const ushort* __restrict__ agg, const ushort* __restrict__ xb_cur,
    const ushort* __restrict__ wfc,   // this layer's packed gi weights [3][16][32][64][8]
    const ushort* __restrict__ wfh,   // packed w_hh                  [3][16][32][64][8]
    const float* __restrict__ b_ih, const float* __restrict__ b_hh,
    ushort* __restrict__ outB, float* __restrict__ outF)
{
    const int x  = blockIdx.x & 7;           // XCD slot
    const int n  = blockIdx.x >> 3;
    const int by = n & 7;                    // col-block (64 cols)
    const int bx = x + ((n >> 3) << 3);      // row-block; 8 col-slices consecutive/XCD
    if (bx >= NBX) return;
    const int n0 = bx * 128;
    const int t = threadIdx.x, w = t >> 6, lane = t & 63;
    const int lrow = lane & 31, lhi = lane >> 5;
    const int wr = w >> 1, wc = w & 1;
    const int wrow = wr << 6;                // 0 / 64
    const int cb = by * 2 + wc;              // 32-col block 0..15

    floatx16 a_sr[2] = {}, a_sz[2] = {}, a_in[2] = {}, a_hn[2] = {};

    // activation row pointers: lane reads 16B of its row at k-offset kk*16 + lhi*8
    int r0 = n0 + wrow + lrow;       if (r0 >= N_NODES) r0 = N_NODES - 1;
    int r1 = n0 + wrow + 32 + lrow;  if (r1 >= N_NODES) r1 = N_NODES - 1;
    const ushort* pa0 = agg    + (size_t)r0 * HIDDEN + lhi * 8;
    const ushort* pa1 = agg    + (size_t)r1 * HIDDEN + lhi * 8;
    const ushort* px0 = xb_cur + (size_t)r0 * HIDDEN + lhi * 8;
    const ushort* px1 = xb_cur + (size_t)r1 * HIDDEN + lhi * 8;
    // weight fragment pointers: contiguous 1KB per (g,cb,kk); advance 512 ushort/kk
    const size_t wo = ((size_t)cb * 32) * 512 + (size_t)lane * 8;
    const ushort* pw0 = wfc            + wo;   // gi r
    const ushort* pw1 = wfc + 262144   + wo;   // gi z
    const ushort* pw2 = wfc + 524288   + wo;   // gi n
    const ushort* pw3 = wfh            + wo;   // hh r
    const ushort* pw4 = wfh + 262144   + wo;   // hh z
    const ushort* pw5 = wfh + 524288   + wo;   // hh n

    #pragma unroll 4
    for (int kk = 0; kk < 32; ++kk) {
        short8 av0 = *(const short8*)(pa0 + kk * 16);
        short8 av1 = *(const short8*)(pa1 + kk * 16);
        short8 xv0 = *(const short8*)(px0 + kk * 16);
        short8 xv1 = *(const short8*)(px1 + kk * 16);
        short8 B0  = *(const short8*)(pw0 + (size_t)kk * 512);
        short8 B1  = *(const short8*)(pw1 + (size_t)kk * 512);
        short8 B2  = *(const short8*)(pw2 + (size_t)kk * 512);
        short8 B3  = *(const short8*)(pw3 + (size_t)kk * 512);
        short8 B4  = *(const short8*)(pw4 + (size_t)kk * 512);
        short8 B5  = *(const short8*)(pw5 + (size_t)kk * 512);
        a_sr[0] = mfma32(av0, B0, a_sr[0]);  a_sr[0] = mfma32(xv0, B3, a_sr[0]);
        a_sr[1] = mfma32(av1, B0, a_sr[1]);  a_sr[1] = mfma32(xv1, B3, a_sr[1]);
        a_sz[0] = mfma32(av0, B1, a_sz[0]);  a_sz[0] = mfma32(xv0, B4, a_sz[0]);
        a_sz[1] = mfma32(av1, B1, a_sz[1]);  a_sz[1] = mfma32(xv1, B4, a_sz[1]);
        a_in[0] = mfma32(av0, B2, a_in[0]);  a_in[1] = mfma32(av1, B2, a_in[1]);
        a_hn[0] = mfma32(xv0, B5, a_hn[0]);  a_hn[1] = mfma32(xv1, B5, a_hn[1]);
    }

    // epilogue: C/D map (32x32): col = lane&31, row = (reg&3) + 8*(reg>>2) + 4*(lane>>5)
    const int colL = (cb << 5) + lrow;
    const float bir = b_ih[colL] + b_hh[colL];
    const float biz = b_ih[HIDDEN + colL] + b_hh[HIDDEN + colL];
    const float bin = b_ih[2 * HIDDEN + colL];
    const float bhn = b_hh[2 * HIDDEN + colL];
    #pragma unroll
    for (int rf = 0; rf < 2; ++rf) {
        #pragma unroll
        for (int rg = 0; rg < 16; ++rg) {
            const int row = n0 + wrow + rf * 32 + (rg & 3) + ((rg >> 2) << 3) + (lhi << 2);
            if (row >= N_NODES) continue;
            float vsr = a_sr[rf][rg] + bir;
            float vsz = a_sz[rf][rg] + biz;
            float vin = a_in[rf][rg] + bin;
            float vhn = a_hn[rf][rg] + bhn;
            float rr = 1.f / (1.f + __expf(-vsr));
            float zz = 1.f / (1.f + __expf(-vsz));
            float nn = tanhf(vin + rr * vhn);
            float h  = bf2f(xb_cur[(size_t)row * HIDDEN + colL]);
            float out = (1.f - zz) * nn + zz * h;
            if (F32OUT) outF[(size_t)row * HIDDEN + colL] = out;
            else        outB[(size_t)row * HIDDEN + colL] = f2bf(out);
        }
    }
}

extern "C" void kernel_launch(void* const* d_in, const int* in_sizes, int n_in,
                              void* d_out, int out_size, void* d_ws, size_t ws_size,
                              hipStream_t stream) {
    const int*   inputs = (const int*)d_in[0];
    const int*   A      = (const int*)d_in[1];
    const float* emb    = (const float*)d_in[2];
    const float* weight = (const float*)d_in[3];
    const float* w_ih   = (const float*)d_in[4];
    const float* w_hh   = (const float*)d_in[5];
    const float* b_ih   = (const float*)d_in[6];
    const float* b_hh   = (const float*)d_in[7];

    // ws: WihB 1.6 + Wb 1.05 + WFc 3.1 + WFhh 1.6 + bufA 51.2 + bufB 51.2 + sort 1.4 ≈ 111 MB
    // ax for layer 0 lives in d_out (51.2 of 102.4 MB); layer 1 ax reuses bufA.
    char* ws = (char*)d_ws;
    size_t off = 0;
    auto alloc = [&](size_t bytes) { void* p = ws + off; off += (bytes + 255) & ~255ull; return p; };
    ushort* WihB      = (ushort*)alloc((size_t)3 * HIDDEN * HIDDEN * sizeof(ushort));
    ushort* Wb        = (ushort*)alloc((size_t)2 * HIDDEN * HIDDEN * sizeof(ushort));
    ushort* WFc       = (ushort*)alloc((size_t)2 * 3 * HIDDEN * HIDDEN * sizeof(ushort));
    ushort* WFhh      = (ushort*)alloc((size_t)3 * HIDDEN * HIDDEN * sizeof(ushort));
    ushort* bufA      = (ushort*)alloc((size_t)N_NODES * HIDDEN * sizeof(ushort));
    ushort* bufB      = (ushort*)alloc((size_t)N_NODES * HIDDEN * sizeof(ushort));
    int*    count     = (int*)alloc((size_t)N_NODES * sizeof(int));
    int*    row_start = (int*)alloc((size_t)(N_NODES + 1) * sizeof(int));
    int*    cursor    = (int*)alloc((size_t)N_NODES * sizeof(int));
    int*    esrc      = (int*)alloc((size_t)N_EDGES * sizeof(int));
    ushort* ax0       = (ushort*)d_out;

    const int nW3 = 3 * HIDDEN * HIDDEN, nW2 = 2 * HIDDEN * HIDDEN;
    const size_t WF_L = (size_t)3 * HIDDEN * HIDDEN;   // per-layer packed-weight stride

    k_cvt8<<<(nW3 / 8 + 255) / 256, 256, 0, stream>>>(w_ih, WihB, nW3);
    k_cvt8<<<(nW2 / 8 + 255) / 256, 256, 0, stream>>>(weight, Wb, nW2);
    k_pack_hh<<<(nW3 / 8 + 255) / 256, 256, 0, stream>>>(w_hh, WFhh);
    k_gemm_w<<<dim3(12, 4, 2), 256, 0, stream>>>(WihB, Wb, WFc);   // frag-major Wc

    k_gather<<<(N_NODES * 64 + 255) / 256, 256, 0, stream>>>(inputs, emb, bufA);

    hipMemsetAsync(count, 0, (size_t)N_NODES * sizeof(int), stream);
    k_hist<<<(N_EDGES + 255) / 256, 256, 0, stream>>>(inputs, A, count);
    k_scan<<<1, SCAN_T, 0, stream>>>(count, row_start, cursor);
    k_place<<<(N_EDGES + 255) / 256, 256, 0, stream>>>(inputs, A, cursor, esrc);

    dim3 gGru(8 * 8 * ((NBX + 7) / 8));   // x(=XCD) * by(8) * row-groups
    dim3 ga((N_NODES + 3) / 4);

    // Layer 0: ax0 = segsum(x0) -> d_out region; GRU(ax0, x0=bufA) -> bufB
    k_agg<<<ga, 256, 0, stream>>>(row_start, esrc, bufA, ax0);
    k_gru7<false><<<gGru, 256, 0, stream>>>(ax0, bufA, WFc, WFhh, b_ih, b_hh, bufB, nullptr);

    // Layer 1: ax1 = segsum(x1) -> bufA (x0 dead); GRU(ax1, x1=bufB) -> f32 d_out
    k_agg<<<ga, 256, 0, stream>>>(row_start, esrc, bufB, bufA);
    k_gru7<true><<<gGru, 256, 0, stream>>>(bufA, bufB, WFc + WF_L, WFhh, b_ih, b_hh,
                                           nullptr, (float*)d_out);
}

// Round 7
// 900.726 us; speedup vs baseline: 1.3080x; 1.3080x over previous
//
#include <hip/hip_runtime.h>
#include <stdint.h>

#define N_NODES 50000
#define HIDDEN  512
#define N_EDGES 200000

#define BK 32
#define LDP 40   // padded LDS row stride (k_gemm_w only)
#define NBX ((N_NODES + 127) / 128)

typedef __attribute__((ext_vector_type(8)))  short short8;
typedef __attribute__((ext_vector_type(4)))  float floatx4;
typedef __attribute__((ext_vector_type(16))) float floatx16;

__device__ inline float bf2f(ushort u) {
    union { uint32_t u; float f; } v; v.u = ((uint32_t)u) << 16; return v.f;
}
__device__ inline ushort f2bf(float f) {
    union { float f; uint32_t u; } v; v.f = f;
    uint32_t r = v.u + 0x7fffu + ((v.u >> 16) & 1u);   // round-to-nearest-even
    return (ushort)(r >> 16);
}
__device__ inline floatx4 mfma16(short8 a, short8 b, floatx4 c) {
    return __builtin_amdgcn_mfma_f32_16x16x32_bf16(a, b, c, 0, 0, 0);
}
__device__ inline floatx16 mfma32(short8 a, short8 b, floatx16 c) {
    return __builtin_amdgcn_mfma_f32_32x32x16_bf16(a, b, c, 0, 0, 0);
}
// async global->LDS, 16B per lane; lds dest is wave-uniform base + lane*16,
// global src address is PER-LANE (pre-swizzled gather is legal).
__device__ inline void gld16(const void* g, void* l) {
    __builtin_amdgcn_global_load_lds(
        (const __attribute__((address_space(1))) unsigned int*)g,
        (__attribute__((address_space(3))) unsigned int*)l, 16, 0, 0);
}
// inputs is arange(N_NODES); if harness kept int64, the int32 view is [0,0,1,0,2,0,...]
__device__ inline bool idx_is64(const int* __restrict__ inputs) {
    return inputs[1] == 0 && inputs[2] == 1;
}

// x = bf16(emb[inputs]) : 8 f32 -> 8 bf16 per thread
__global__ void k_gather(const int* __restrict__ inputs, const float* __restrict__ emb,
                         ushort* __restrict__ xb) {
    bool is64 = idx_is64(inputs);
    int t = blockIdx.x * blockDim.x + threadIdx.x;   // N_NODES*64 threads
    int row = t >> 6, s8 = (t & 63) << 3;
    if (row >= N_NODES) return;
    int srow = is64 ? inputs[2 * row] : inputs[row];
    srow = srow < 0 ? 0 : (srow >= N_NODES ? N_NODES - 1 : srow);
    const float* src = emb + (size_t)srow * HIDDEN + s8;
    float4 v0 = *(const float4*)(src);
    float4 v1 = *(const float4*)(src + 4);
    ushort o[8] = { f2bf(v0.x), f2bf(v0.y), f2bf(v0.z), f2bf(v0.w),
                    f2bf(v1.x), f2bf(v1.y), f2bf(v1.z), f2bf(v1.w) };
    *(uint4*)(xb + (size_t)row * HIDDEN + s8) = *(uint4*)o;
}

// generic f32 -> bf16 (8/thread), row-major preserved
__global__ void k_cvt8(const float* __restrict__ src, ushort* __restrict__ dst, int n) {
    int t = blockIdx.x * blockDim.x + threadIdx.x;
    int base = t * 8;
    if (base >= n) return;
    float4 v0 = *(const float4*)(src + base);
    float4 v1 = *(const float4*)(src + base + 4);
    ushort o[8] = { f2bf(v0.x), f2bf(v0.y), f2bf(v0.z), f2bf(v0.w),
                    f2bf(v1.x), f2bf(v1.y), f2bf(v1.z), f2bf(v1.w) };
    *(uint4*)(dst + base) = *(uint4*)o;
}

// Fragment-major weight layout for mfma_32x32x16_bf16 B operand:
// element (grow in [0,1536), k in [0,512)):
//   g = grow>>9, col = grow&511, cb = col>>5, lanelo = col&31,
//   kk = k>>4, hi = (k>>3)&1, j = k&7, lane = lanelo + hi*32
//   idx = (((g*16 + cb)*32 + kk)*64 + lane)*8 + j
// -> each (g,cb,kk) frag is a contiguous 1KB panel; wave load = base + lane*16.
__device__ inline size_t wf_index(int grow, int k) {
    int g3 = grow >> 9, gcol = grow & 511;
    int cb = gcol >> 5, llo = gcol & 31;
    int kk = k >> 4, hi = (k >> 3) & 1, jj = k & 7;
    return ((((size_t)g3 * 16 + cb) * 32 + kk) * 64 + llo + hi * 32) * 8 + jj;
}

// Wc[l][g][k] = sum_j wih[g][j] * W[l][k][j]  (combined gi weights), written frag-major.
// A = WihB [1536][512] contig-j ; B = Wb[l] [512][512] contig-j ; M=1536,N=512,K=512.
__global__ __launch_bounds__(256) void k_gemm_w(const ushort* __restrict__ Aw,
                                                const ushort* __restrict__ Bw,
                                                ushort* __restrict__ Cw) {
    __shared__ ushort As[128][LDP];
    __shared__ ushort Bs[128][LDP];
    const int l = blockIdx.z;
    const ushort* Bp = Bw + (size_t)l * HIDDEN * HIDDEN;
    ushort* Cp = Cw + (size_t)l * 3 * HIDDEN * HIDDEN;
    const int n0 = blockIdx.x * 128, c0 = blockIdx.y * 128;
    const int t = threadIdx.x;
    const int wave = t >> 6, lane = t & 63;
    const int wm = (wave >> 1) << 6, wn = (wave & 1) << 6;
    const int fr = lane & 15, fk = (lane >> 4) << 3;
    const int lm = t >> 2, lk = (t & 3) << 3;
    floatx4 acc[4][4] = {};

    for (int k0 = 0; k0 < HIDDEN; k0 += BK) {
        *(uint4*)&As[lm][lk]      = *(const uint4*)(Aw + (size_t)(n0 + lm) * HIDDEN + k0 + lk);
        *(uint4*)&As[64 + lm][lk] = *(const uint4*)(Aw + (size_t)(n0 + 64 + lm) * HIDDEN + k0 + lk);
        *(uint4*)&Bs[lm][lk]      = *(const uint4*)(Bp + (size_t)(c0 + lm) * HIDDEN + k0 + lk);
        *(uint4*)&Bs[64 + lm][lk] = *(const uint4*)(Bp + (size_t)(c0 + 64 + lm) * HIDDEN + k0 + lk);
        __syncthreads();
        short8 aa[4], bb[4];
        #pragma unroll
        for (int i = 0; i < 4; ++i) {
            aa[i] = *(const short8*)&As[wm + i * 16 + fr][fk];
            bb[i] = *(const short8*)&Bs[wn + i * 16 + fr][fk];
        }
        #pragma unroll
        for (int i = 0; i < 4; ++i)
            #pragma unroll
            for (int j = 0; j < 4; ++j)
                acc[i][j] = mfma16(aa[i], bb[j], acc[i][j]);
        __syncthreads();
    }
    const int er = (lane >> 4) << 2, ec = lane & 15;
    #pragma unroll
    for (int i = 0; i < 4; ++i)
        #pragma unroll
        for (int j = 0; j < 4; ++j)
            #pragma unroll
            for (int r = 0; r < 4; ++r) {
                int grow = n0 + wm + i * 16 + er + r;   // gi-output row (gate dim)
                int kcol = c0 + wn + j * 16 + ec;       // k dim
                Cp[wf_index(grow, kcol)] = f2bf(acc[i][j][r]);
            }
}

// pack w_hh (f32 [1536][512]) into fragment-major bf16
__global__ void k_pack_hh(const float* __restrict__ whh, ushort* __restrict__ wfh) {
    int t = blockIdx.x * blockDim.x + threadIdx.x;   // 1536*64 threads
    if (t >= 3 * HIDDEN * HIDDEN / 8) return;
    int grow = t >> 6, k = (t & 63) << 3;
    const float* src = whh + (size_t)grow * HIDDEN + k;
    ushort o[8];
    #pragma unroll
    for (int j = 0; j < 8; ++j) o[j] = f2bf(src[j]);
    *(uint4*)(wfh + wf_index(grow, k)) = *(uint4*)o;   // j=0..7 contiguous -> 16B store
}

// ---- counting sort of edges by dst (once per call; graph shared by both layers) ----
__global__ void k_hist(const int* __restrict__ inputs, const int* __restrict__ A,
                       int* __restrict__ count) {
    bool is64 = idx_is64(inputs);
    int e = blockIdx.x * blockDim.x + threadIdx.x;
    if (e >= N_EDGES) return;
    int d = is64 ? A[2 * (N_EDGES + e)] : A[N_EDGES + e];
    if (d < 0 || d >= N_NODES) return;
    atomicAdd(count + d, 1);
}

#define SCAN_T 1024
__global__ __launch_bounds__(SCAN_T) void k_scan(const int* __restrict__ count,
                                                 int* __restrict__ row_start,
                                                 int* __restrict__ cursor) {
    __shared__ int part[SCAN_T];
    const int t = threadIdx.x;
    const int chunk = (N_NODES + SCAN_T - 1) / SCAN_T;   // 49
    const int base = t * chunk;
    int s = 0;
    for (int i = 0; i < chunk; ++i) {
        int idx = base + i;
        if (idx < N_NODES) s += count[idx];
    }
    part[t] = s;
    __syncthreads();
    for (int off = 1; off < SCAN_T; off <<= 1) {
        int add = (t >= off) ? part[t - off] : 0;
        __syncthreads();
        part[t] += add;
        __syncthreads();
    }
    int running = (t == 0) ? 0 : part[t - 1];
    for (int i = 0; i < chunk; ++i) {
        int idx = base + i;
        if (idx < N_NODES) {
            row_start[idx] = running;
            cursor[idx] = running;
            running += count[idx];
        }
    }
    if (t == 0) row_start[N_NODES] = part[SCAN_T - 1];
}

__global__ void k_place(const int* __restrict__ inputs, const int* __restrict__ A,
                        int* __restrict__ cursor, int* __restrict__ esrc) {
    bool is64 = idx_is64(inputs);
    int e = blockIdx.x * blockDim.x + threadIdx.x;
    if (e >= N_EDGES) return;
    int s, d;
    if (is64) { s = A[2 * e]; d = A[2 * (N_EDGES + e)]; }
    else      { s = A[e];     d = A[N_EDGES + e]; }
    if (s < 0 || s >= N_NODES || d < 0 || d >= N_NODES) return;
    int pos = atomicAdd(cursor + d, 1);
    esrc[pos] = s;
}

// ax[n] = sum_{e: dst=n} x[src[e]] : one wave per node, lane owns 8 cols, f32 acc -> bf16
__global__ __launch_bounds__(256) void k_agg(const int* __restrict__ row_start,
                                             const int* __restrict__ esrc,
                                             const ushort* __restrict__ x,
                                             ushort* __restrict__ ax) {
    int node = blockIdx.x * 4 + (threadIdx.x >> 6);
    if (node >= N_NODES) return;
    int lane = threadIdx.x & 63;
    int q = lane << 3;
    int beg = row_start[node], end = row_start[node + 1];
    float acc[8] = {};
    for (int i = beg; i < end; ++i) {
        int s = esrc[i];
        uint4 v = *(const uint4*)(x + (size_t)s * HIDDEN + q);
        const ushort* u = (const ushort*)&v;
        #pragma unroll
        for (int j = 0; j < 8; ++j) acc[j] += bf2f(u[j]);
    }
    ushort o[8];
    #pragma unroll
    for (int j = 0; j < 8; ++j) o[j] = f2bf(acc[j]);
    *(uint4*)(ax + (size_t)node * HIDDEN + q) = *(uint4*)o;
}

// Fused GRU v8: 8-phase-style fine interleave (T3+T4+T5, m201 template).
// Geometry: 512 threads = 8 waves (2 row-halves x 4 col-groups); BM=128, BN=128,
// K-step=32 split into 4 phases. Per phase: {vmcnt(6)+s_barrier -> 5x ds_read_b128
// -> 2x gld16 (NEXT step, same phase slots) -> setprio(1) -> 6x mfma32 -> setprio(0)}.
// vmcnt invariant: every phase start has exactly 8 outstanding gld16 per wave, and
// the oldest 2 are precisely this phase's slots (staged 4 phases = 1 full step ago)
// -> vmcnt(6) retires them with ~1800 cyc of lead; vmcnt NEVER drains to 0 in-loop.
// LDS/buffer = 64 slots x 1KB (A:8, X:8, W:48), 2 buffers = 128 KB. All ds_reads
// lane-linear 16B (0 conflicts, proven v5-v7). Final step stages garbage into the
// dead buffer (sources stay in-workspace; never read) to keep the vmcnt invariant.
template<bool F32OUT>
__global__ __launch_bounds__(512, 2) void k_gru8(
    const ushort* __restrict__ agg, const ushort* __restrict__ xb_cur,
    const ushort* __restrict__ wfc,   // this layer's packed gi weights [3][16][32][64][8]
    const ushort* __restrict__ wfh,   // packed w_hh                  [3][16][32][64][8]
    const float* __restrict__ b_ih, const float* __restrict__ b_hh,
    ushort* __restrict__ outB, float* __restrict__ outF)
{
    __shared__ ushort S[2 * 32768];          // [buf][slot 0..63][512] ushort, 128 KB
    const int x  = blockIdx.x & 7;           // XCD slot
    const int n  = blockIdx.x >> 3;
    const int by = n & 3;                    // col-block (128 cols)
    const int bx = x + ((n >> 2) << 3);      // row-block; 4 col-slices consecutive/XCD
    if (bx >= NBX) return;
    const int n0 = bx * 128;
    const int t = threadIdx.x, w = t >> 6, lane = t & 63;
    const int lrow = lane & 31, lhi = lane >> 5;
    const int wr = w >> 2, wc = w & 3;       // row-half 0/1, col-group 0..3
    const int cb0 = by * 4;
    const int cb = cb0 + wc;                 // this wave's 32-col block in [0,16)

    floatx16 a_sr[2] = {}, a_sz[2] = {}, a_in[2] = {}, a_hn[2] = {};

    const ushort* wB[6] = { wfc, wfc + 262144, wfc + 524288,    // gi r,z,n
                            wfh, wfh + 262144, wfh + 524288 };  // hh r,z,n

    // ---- staging descriptors: wave w stages frags f = 2w, 2w+1 of each phase ----
    // slot(p, f) = p*16 + f. f<4: act (A for even p, X for odd p), rows f*32..+32;
    // f>=4: weight panel g = (f-4)/4 + 3*(p&1), col-group cbl = (f-4)&3.
    const ushort* sp[8];   // per-lane global source, q = p*2 + e
    int           adv[8];  // ushort advance per K32 step
    int           off[8];  // LDS ushort offset within a buffer
    #pragma unroll
    for (int q = 0; q < 8; ++q) {
        const int p = q >> 1, e = q & 1;
        const int f = 2 * w + e;             // frag index in [0,16)
        const int sub = p & 1, kh = p >> 1;
        off[q] = (p * 16 + f) * 512;
        if (f < 4) {                          // waves 0,1: activations
            int row = n0 + f * 32 + lrow;
            if (row >= N_NODES) row = N_NODES - 1;   // dup row; epilogue skips OOB
            const ushort* arr = sub ? xb_cur : agg;
            sp[q] = arr + (size_t)row * HIDDEN + kh * 16 + lhi * 8;
            adv[q] = 32;
        } else {                              // waves 2..7: weights
            const int fw = f - 4, j = fw >> 2, cbl = fw & 3, g = j + 3 * sub;
            sp[q] = wB[g] + ((size_t)(cb0 + cbl) * 32 + kh) * 512 + (size_t)lane * 8;
            adv[q] = 1024;
        }
    }

    // prologue: stage step 0 into buf 0 (8 issues, phase-major order)
    #pragma unroll
    for (int q = 0; q < 8; ++q) { gld16(sp[q], S + off[q]); sp[q] += adv[q]; }

    // one phase: retire this phase's 2 staged frags, read 5 operand frags, issue
    // next step's 2 stages, 6 MFMA. ACC0/1/2 chosen by sub (av: sr,sz,in / xv: sr,sz,hn).
    #define PHASE(p, A0, A1, A2)  {                                                  \
        asm volatile("s_waitcnt vmcnt(6)\n\ts_barrier" ::: "memory");                \
        const ushort* P = S + (size_t)cur * 32768 + (p) * 16 * 512 + (size_t)lane * 8;\
        short8 v0 = *(const short8*)(P + (wr * 2 + 0) * 512);                        \
        short8 v1 = *(const short8*)(P + (wr * 2 + 1) * 512);                        \
        short8 W0 = *(const short8*)(P + (4 + 0 * 4 + wc) * 512);                    \
        short8 W1 = *(const short8*)(P + (4 + 1 * 4 + wc) * 512);                    \
        short8 W2 = *(const short8*)(P + (4 + 2 * 4 + wc) * 512);                    \
        ushort* D = S + (size_t)(cur ^ 1) * 32768;                                   \
        gld16(sp[(p) * 2 + 0], D + off[(p) * 2 + 0]); sp[(p) * 2 + 0] += adv[(p) * 2 + 0]; \
        gld16(sp[(p) * 2 + 1], D + off[(p) * 2 + 1]); sp[(p) * 2 + 1] += adv[(p) * 2 + 1]; \
        __builtin_amdgcn_s_setprio(1);                                               \
        A0[0] = mfma32(v0, W0, A0[0]);  A0[1] = mfma32(v1, W0, A0[1]);               \
        A1[0] = mfma32(v0, W1, A1[0]);  A1[1] = mfma32(v1, W1, A1[1]);               \
        A2[0] = mfma32(v0, W2, A2[0]);  A2[1] = mfma32(v1, W2, A2[1]);               \
        __builtin_amdgcn_s_setprio(0); }

    for (int ks = 0; ks < 16; ++ks) {
        const int cur = ks & 1;
        PHASE(0, a_sr, a_sz, a_in)   // kk=0, av-based
        PHASE(1, a_sr, a_sz, a_hn)   // kk=0, xv-based
        PHASE(2, a_sr, a_sz, a_in)   // kk=1, av-based
        PHASE(3, a_sr, a_sz, a_hn)   // kk=1, xv-based
    }
    #undef PHASE

    // epilogue: C/D map (32x32): col = lane&31, row = (reg&3) + 8*(reg>>2) + 4*(lane>>5)
    const int colL = (cb << 5) + lrow;
    const float bir = b_ih[colL] + b_hh[colL];
    const float biz = b_ih[HIDDEN + colL] + b_hh[HIDDEN + colL];
    const float bin = b_ih[2 * HIDDEN + colL];
    const float bhn = b_hh[2 * HIDDEN + colL];
    #pragma unroll
    for (int rf = 0; rf < 2; ++rf) {
        #pragma unroll
        for (int rg = 0; rg < 16; ++rg) {
            const int row = n0 + wr * 64 + rf * 32 + (rg & 3) + ((rg >> 2) << 3) + (lhi << 2);
            if (row >= N_NODES) continue;
            float vsr = a_sr[rf][rg] + bir;
            float vsz = a_sz[rf][rg] + biz;
            float vin = a_in[rf][rg] + bin;
            float vhn = a_hn[rf][rg] + bhn;
            float rr = 1.f / (1.f + __expf(-vsr));
            float zz = 1.f / (1.f + __expf(-vsz));
            float nn = tanhf(vin + rr * vhn);
            float h  = bf2f(xb_cur[(size_t)row * HIDDEN + colL]);
            float out = (1.f - zz) * nn + zz * h;
            if (F32OUT) outF[(size_t)row * HIDDEN + colL] = out;
            else        outB[(size_t)row * HIDDEN + colL] = f2bf(out);
        }
    }
}

extern "C" void kernel_launch(void* const* d_in, const int* in_sizes, int n_in,
                              void* d_out, int out_size, void* d_ws, size_t ws_size,
                              hipStream_t stream) {
    const int*   inputs = (const int*)d_in[0];
    const int*   A      = (const int*)d_in[1];
    const float* emb    = (const float*)d_in[2];
    const float* weight = (const float*)d_in[3];
    const float* w_ih   = (const float*)d_in[4];
    const float* w_hh   = (const float*)d_in[5];
    const float* b_ih   = (const float*)d_in[6];
    const float* b_hh   = (const float*)d_in[7];

    // ws: WihB 1.6 + Wb 1.05 + WFc 3.1 + WFhh 1.6 + bufA 51.2 + bufB 51.2 + sort 1.4 ≈ 111 MB
    // ax for layer 0 lives in d_out (51.2 of 102.4 MB); layer 1 ax reuses bufA.
    char* ws = (char*)d_ws;
    size_t off = 0;
    auto alloc = [&](size_t bytes) { void* p = ws + off; off += (bytes + 255) & ~255ull; return p; };
    ushort* WihB      = (ushort*)alloc((size_t)3 * HIDDEN * HIDDEN * sizeof(ushort));
    ushort* Wb        = (ushort*)alloc((size_t)2 * HIDDEN * HIDDEN * sizeof(ushort));
    ushort* WFc       = (ushort*)alloc((size_t)2 * 3 * HIDDEN * HIDDEN * sizeof(ushort));
    ushort* WFhh      = (ushort*)alloc((size_t)3 * HIDDEN * HIDDEN * sizeof(ushort));
    ushort* bufA      = (ushort*)alloc((size_t)N_NODES * HIDDEN * sizeof(ushort));
    ushort* bufB      = (ushort*)alloc((size_t)N_NODES * HIDDEN * sizeof(ushort));
    int*    count     = (int*)alloc((size_t)N_NODES * sizeof(int));
    int*    row_start = (int*)alloc((size_t)(N_NODES + 1) * sizeof(int));
    int*    cursor    = (int*)alloc((size_t)N_NODES * sizeof(int));
    int*    esrc      = (int*)alloc((size_t)N_EDGES * sizeof(int));
    ushort* ax0       = (ushort*)d_out;

    const int nW3 = 3 * HIDDEN * HIDDEN, nW2 = 2 * HIDDEN * HIDDEN;
    const size_t WF_L = (size_t)3 * HIDDEN * HIDDEN;   // per-layer packed-weight stride

    k_cvt8<<<(nW3 / 8 + 255) / 256, 256, 0, stream>>>(w_ih, WihB, nW3);
    k_cvt8<<<(nW2 / 8 + 255) / 256, 256, 0, stream>>>(weight, Wb, nW2);
    k_pack_hh<<<(nW3 / 8 + 255) / 256, 256, 0, stream>>>(w_hh, WFhh);
    k_gemm_w<<<dim3(12, 4, 2), 256, 0, stream>>>(WihB, Wb, WFc);   // frag-major Wc

    k_gather<<<(N_NODES * 64 + 255) / 256, 256, 0, stream>>>(inputs, emb, bufA);

    hipMemsetAsync(count, 0, (size_t)N_NODES * sizeof(int), stream);
    k_hist<<<(N_EDGES + 255) / 256, 256, 0, stream>>>(inputs, A, count);
    k_scan<<<1, SCAN_T, 0, stream>>>(count, row_start, cursor);
    k_place<<<(N_EDGES + 255) / 256, 256, 0, stream>>>(inputs, A, cursor, esrc);

    dim3 gGru(8 * 4 * ((NBX + 7) / 8));   // x(=XCD) * by(4) * row-groups
    dim3 ga((N_NODES + 3) / 4);

    // Layer 0: ax0 = segsum(x0) -> d_out region; GRU(ax0, x0=bufA) -> bufB
    k_agg<<<ga, 256, 0, stream>>>(row_start, esrc, bufA, ax0);
    k_gru8<false><<<gGru, 512, 0, stream>>>(ax0, bufA, WFc, WFhh, b_ih, b_hh, bufB, nullptr);

    // Layer 1: ax1 = segsum(x1) -> bufA (x0 dead); GRU(ax1, x1=bufB) -> f32 d_out
    k_agg<<<ga, 256, 0, stream>>>(row_start, esrc, bufB, bufA);
    k_gru8<true><<<gGru, 512, 0, stream>>>(bufA, bufB, WFc + WF_L, WFhh, b_ih, b_hh,
                                           nullptr, (float*)d_out);
}

// Round 8
// 894.868 us; speedup vs baseline: 1.3165x; 1.0065x over previous
//
#include <hip/hip_runtime.h>
#include <stdint.h>

#define N_NODES 50000
#define HIDDEN  512
#define N_EDGES 200000

#define BK 32
#define LDP 40   // padded LDS row stride (k_gemm_w only)
#define NBX ((N_NODES + 127) / 128)

typedef __attribute__((ext_vector_type(8)))  short short8;
typedef __attribute__((ext_vector_type(4)))  float floatx4;
typedef __attribute__((ext_vector_type(16))) float floatx16;

__device__ inline float bf2f(ushort u) {
    union { uint32_t u; float f; } v; v.u = ((uint32_t)u) << 16; return v.f;
}
__device__ inline ushort f2bf(float f) {
    union { float f; uint32_t u; } v; v.f = f;
    uint32_t r = v.u + 0x7fffu + ((v.u >> 16) & 1u);   // round-to-nearest-even
    return (ushort)(r >> 16);
}
__device__ inline floatx4 mfma16(short8 a, short8 b, floatx4 c) {
    return __builtin_amdgcn_mfma_f32_16x16x32_bf16(a, b, c, 0, 0, 0);
}
__device__ inline floatx16 mfma32(short8 a, short8 b, floatx16 c) {
    return __builtin_amdgcn_mfma_f32_32x32x16_bf16(a, b, c, 0, 0, 0);
}
// async global->LDS, 16B per lane; lds dest is wave-uniform base + lane*16,
// global src address is PER-LANE (pre-swizzled gather is legal).
__device__ inline void gld16(const void* g, void* l) {
    __builtin_amdgcn_global_load_lds(
        (const __attribute__((address_space(1))) unsigned int*)g,
        (__attribute__((address_space(3))) unsigned int*)l, 16, 0, 0);
}
// inputs is arange(N_NODES); if harness kept int64, the int32 view is [0,0,1,0,2,0,...]
__device__ inline bool idx_is64(const int* __restrict__ inputs) {
    return inputs[1] == 0 && inputs[2] == 1;
}

// x = bf16(emb[inputs]) : 8 f32 -> 8 bf16 per thread
__global__ void k_gather(const int* __restrict__ inputs, const float* __restrict__ emb,
                         ushort* __restrict__ xb) {
    bool is64 = idx_is64(inputs);
    int t = blockIdx.x * blockDim.x + threadIdx.x;   // N_NODES*64 threads
    int row = t >> 6, s8 = (t & 63) << 3;
    if (row >= N_NODES) return;
    int srow = is64 ? inputs[2 * row] : inputs[row];
    srow = srow < 0 ? 0 : (srow >= N_NODES ? N_NODES - 1 : srow);
    const float* src = emb + (size_t)srow * HIDDEN + s8;
    float4 v0 = *(const float4*)(src);
    float4 v1 = *(const float4*)(src + 4);
    ushort o[8] = { f2bf(v0.x), f2bf(v0.y), f2bf(v0.z), f2bf(v0.w),
                    f2bf(v1.x), f2bf(v1.y), f2bf(v1.z), f2bf(v1.w) };
    *(uint4*)(xb + (size_t)row * HIDDEN + s8) = *(uint4*)o;
}

// generic f32 -> bf16 (8/thread), row-major preserved
__global__ void k_cvt8(const float* __restrict__ src, ushort* __restrict__ dst, int n) {
    int t = blockIdx.x * blockDim.x + threadIdx.x;
    int base = t * 8;
    if (base >= n) return;
    float4 v0 = *(const float4*)(src + base);
    float4 v1 = *(const float4*)(src + base + 4);
    ushort o[8] = { f2bf(v0.x), f2bf(v0.y), f2bf(v0.z), f2bf(v0.w),
                    f2bf(v1.x), f2bf(v1.y), f2bf(v1.z), f2bf(v1.w) };
    *(uint4*)(dst + base) = *(uint4*)o;
}

// Fragment-major weight layout for mfma_32x32x16_bf16 B operand:
// element (grow in [0,1536), k in [0,512)):
//   g = grow>>9, col = grow&511, cb = col>>5, lanelo = col&31,
//   kk = k>>4, hi = (k>>3)&1, j = k&7, lane = lanelo + hi*32
//   idx = (((g*16 + cb)*32 + kk)*64 + lane)*8 + j
// -> each (g,cb,kk) frag is a contiguous 1KB panel; wave load = base + lane*16.
__device__ inline size_t wf_index(int grow, int k) {
    int g3 = grow >> 9, gcol = grow & 511;
    int cb = gcol >> 5, llo = gcol & 31;
    int kk = k >> 4, hi = (k >> 3) & 1, jj = k & 7;
    return ((((size_t)g3 * 16 + cb) * 32 + kk) * 64 + llo + hi * 32) * 8 + jj;
}

// Wc[l][g][k] = sum_j wih[g][j] * W[l][k][j]  (combined gi weights), written frag-major.
// A = WihB [1536][512] contig-j ; B = Wb[l] [512][512] contig-j ; M=1536,N=512,K=512.
__global__ __launch_bounds__(256) void k_gemm_w(const ushort* __restrict__ Aw,
                                                const ushort* __restrict__ Bw,
                                                ushort* __restrict__ Cw) {
    __shared__ ushort As[128][LDP];
    __shared__ ushort Bs[128][LDP];
    const int l = blockIdx.z;
    const ushort* Bp = Bw + (size_t)l * HIDDEN * HIDDEN;
    ushort* Cp = Cw + (size_t)l * 3 * HIDDEN * HIDDEN;
    const int n0 = blockIdx.x * 128, c0 = blockIdx.y * 128;
    const int t = threadIdx.x;
    const int wave = t >> 6, lane = t & 63;
    const int wm = (wave >> 1) << 6, wn = (wave & 1) << 6;
    const int fr = lane & 15, fk = (lane >> 4) << 3;
    const int lm = t >> 2, lk = (t & 3) << 3;
    floatx4 acc[4][4] = {};

    for (int k0 = 0; k0 < HIDDEN; k0 += BK) {
        *(uint4*)&As[lm][lk]      = *(const uint4*)(Aw + (size_t)(n0 + lm) * HIDDEN + k0 + lk);
        *(uint4*)&As[64 + lm][lk] = *(const uint4*)(Aw + (size_t)(n0 + 64 + lm) * HIDDEN + k0 + lk);
        *(uint4*)&Bs[lm][lk]      = *(const uint4*)(Bp + (size_t)(c0 + lm) * HIDDEN + k0 + lk);
        *(uint4*)&Bs[64 + lm][lk] = *(const uint4*)(Bp + (size_t)(c0 + 64 + lm) * HIDDEN + k0 + lk);
        __syncthreads();
        short8 aa[4], bb[4];
        #pragma unroll
        for (int i = 0; i < 4; ++i) {
            aa[i] = *(const short8*)&As[wm + i * 16 + fr][fk];
            bb[i] = *(const short8*)&Bs[wn + i * 16 + fr][fk];
        }
        #pragma unroll
        for (int i = 0; i < 4; ++i)
            #pragma unroll
            for (int j = 0; j < 4; ++j)
                acc[i][j] = mfma16(aa[i], bb[j], acc[i][j]);
        __syncthreads();
    }
    const int er = (lane >> 4) << 2, ec = lane & 15;
    #pragma unroll
    for (int i = 0; i < 4; ++i)
        #pragma unroll
        for (int j = 0; j < 4; ++j)
            #pragma unroll
            for (int r = 0; r < 4; ++r) {
                int grow = n0 + wm + i * 16 + er + r;   // gi-output row (gate dim)
                int kcol = c0 + wn + j * 16 + ec;       // k dim
                Cp[wf_index(grow, kcol)] = f2bf(acc[i][j][r]);
            }
}

// pack w_hh (f32 [1536][512]) into fragment-major bf16
__global__ void k_pack_hh(const float* __restrict__ whh, ushort* __restrict__ wfh) {
    int t = blockIdx.x * blockDim.x + threadIdx.x;   // 1536*64 threads
    if (t >= 3 * HIDDEN * HIDDEN / 8) return;
    int grow = t >> 6, k = (t & 63) << 3;
    const float* src = whh + (size_t)grow * HIDDEN + k;
    ushort o[8];
    #pragma unroll
    for (int j = 0; j < 8; ++j) o[j] = f2bf(src[j]);
    *(uint4*)(wfh + wf_index(grow, k)) = *(uint4*)o;   // j=0..7 contiguous -> 16B store
}

// ---- counting sort of edges by dst (once per call; graph shared by both layers) ----
__global__ void k_hist(const int* __restrict__ inputs, const int* __restrict__ A,
                       int* __restrict__ count) {
    bool is64 = idx_is64(inputs);
    int e = blockIdx.x * blockDim.x + threadIdx.x;
    if (e >= N_EDGES) return;
    int d = is64 ? A[2 * (N_EDGES + e)] : A[N_EDGES + e];
    if (d < 0 || d >= N_NODES) return;
    atomicAdd(count + d, 1);
}

#define SCAN_T 1024
__global__ __launch_bounds__(SCAN_T) void k_scan(const int* __restrict__ count,
                                                 int* __restrict__ row_start,
                                                 int* __restrict__ cursor) {
    __shared__ int part[SCAN_T];
    const int t = threadIdx.x;
    const int chunk = (N_NODES + SCAN_T - 1) / SCAN_T;   // 49
    const int base = t * chunk;
    int s = 0;
    for (int i = 0; i < chunk; ++i) {
        int idx = base + i;
        if (idx < N_NODES) s += count[idx];
    }
    part[t] = s;
    __syncthreads();
    for (int off = 1; off < SCAN_T; off <<= 1) {
        int add = (t >= off) ? part[t - off] : 0;
        __syncthreads();
        part[t] += add;
        __syncthreads();
    }
    int running = (t == 0) ? 0 : part[t - 1];
    for (int i = 0; i < chunk; ++i) {
        int idx = base + i;
        if (idx < N_NODES) {
            row_start[idx] = running;
            cursor[idx] = running;
            running += count[idx];
        }
    }
    if (t == 0) row_start[N_NODES] = part[SCAN_T - 1];
}

__global__ void k_place(const int* __restrict__ inputs, const int* __restrict__ A,
                        int* __restrict__ cursor, int* __restrict__ esrc) {
    bool is64 = idx_is64(inputs);
    int e = blockIdx.x * blockDim.x + threadIdx.x;
    if (e >= N_EDGES) return;
    int s, d;
    if (is64) { s = A[2 * e]; d = A[2 * (N_EDGES + e)]; }
    else      { s = A[e];     d = A[N_EDGES + e]; }
    if (s < 0 || s >= N_NODES || d < 0 || d >= N_NODES) return;
    int pos = atomicAdd(cursor + d, 1);
    esrc[pos] = s;
}

// ax[n] = sum_{e: dst=n} x[src[e]] : one wave per node, lane owns 8 cols, f32 acc -> bf16
__global__ __launch_bounds__(256) void k_agg(const int* __restrict__ row_start,
                                             const int* __restrict__ esrc,
                                             const ushort* __restrict__ x,
                                             ushort* __restrict__ ax) {
    int node = blockIdx.x * 4 + (threadIdx.x >> 6);
    if (node >= N_NODES) return;
    int lane = threadIdx.x & 63;
    int q = lane << 3;
    int beg = row_start[node], end = row_start[node + 1];
    float acc[8] = {};
    for (int i = beg; i < end; ++i) {
        int s = esrc[i];
        uint4 v = *(const uint4*)(x + (size_t)s * HIDDEN + q);
        const ushort* u = (const ushort*)&v;
        #pragma unroll
        for (int j = 0; j < 8; ++j) acc[j] += bf2f(u[j]);
    }
    ushort o[8];
    #pragma unroll
    for (int j = 0; j < 8; ++j) o[j] = f2bf(acc[j]);
    *(uint4*)(ax + (size_t)node * HIDDEN + q) = *(uint4*)o;
}

// Fused GRU v9 = v8 skeleton with FATTER phases: 2 phases per K=32 step (was 4).
// v8 post-mortem: per-phase fixed cost (barrier arrival + vmcnt + ds_read latency)
// ~1100 cyc vs 388 cyc MFMA work -> 27% MfmaUtil. Merging the kh-split doubles the
// MFMA cluster per barrier round (12 mfma32, 776 pipe-cyc/SIMD) against the same
// fixed cost; barrier rounds per block drop 64 -> 32.
// Geometry unchanged: 512 threads = 8 waves (2 row-halves x 4 col-groups), BM=128,
// BN=128, wave tile 64r x 32c. Per phase: {vmcnt(4)+s_barrier -> 10x ds_read_b128
// -> 4x gld16 (NEXT step, same phase slots) -> setprio(1) -> 12x mfma32 -> setprio(0)}.
// vmcnt invariant: 8 outstanding per wave at every phase start; the oldest 4 are
// exactly this phase's slots (staged 2 phases = 1 full step ago); never drains to 0.
// Buffer = 64 slots x 1KB (phase p slots: act 8 [rg x kh], W 24 [gate x cbl x kh]),
// 2 buffers = 128 KB. All ds_reads lane-linear 16B (0 conflicts, proven v5-v8).
// Final step stages garbage into the dead buffer (sources stay in-workspace).
template<bool F32OUT>
__global__ __launch_bounds__(512, 2) void k_gru9(
    const ushort* __restrict__ agg, const ushort* __restrict__ xb_cur,
    const ushort* __restrict__ wfc,   // this layer's packed gi weights [3][16][32][64][8]
    const ushort* __restrict__ wfh,   // packed w_hh                  [3][16][32][64][8]
    const float* __restrict__ b_ih, const float* __restrict__ b_hh,
    ushort* __restrict__ outB, float* __restrict__ outF)
{
    __shared__ ushort S[2 * 32768];          // [buf][phase 0..1][slot 0..31][512], 128 KB
    const int x  = blockIdx.x & 7;           // XCD slot
    const int n  = blockIdx.x >> 3;
    const int by = n & 3;                    // col-block (128 cols)
    const int bx = x + ((n >> 2) << 3);      // row-block; 4 col-slices consecutive/XCD
    if (bx >= NBX) return;
    const int n0 = bx * 128;
    const int t = threadIdx.x, w = t >> 6, lane = t & 63;
    const int lrow = lane & 31, lhi = lane >> 5;
    const int wr = w >> 2, wc = w & 3;       // row-half 0/1, col-group 0..3
    const int cb0 = by * 4;
    const int cb = cb0 + wc;                 // this wave's 32-col block in [0,16)

    floatx16 a_sr[2] = {}, a_sz[2] = {}, a_in[2] = {}, a_hn[2] = {};

    const ushort* wB[6] = { wfc, wfc + 262144, wfc + 524288,    // gi r,z,n
                            wfh, wfh + 262144, wfh + 524288 };  // hh r,z,n

    // ---- staging descriptors: wave w stages frags f = 4w..4w+3 of each phase ----
    // slot(p, f) = p*32 + f. f<8: act (A for p=0, X for p=1), rg = f>>1, kh = f&1;
    // f>=8: fw=f-8: weight panel g = (fw>>3) + 3p, col-group cbl = (fw>>1)&3, kh = fw&1.
    const ushort* sp[8];   // per-lane global source, q = p*4 + e
    int           adv[8];  // ushort advance per K32 step
    int           off[8];  // LDS ushort offset within a buffer
    #pragma unroll
    for (int q = 0; q < 8; ++q) {
        const int p = q >> 2, e = q & 3;
        const int f = 4 * w + e;             // frag index in [0,32)
        off[q] = (p * 32 + f) * 512;
        if (f < 8) {                          // waves 0,1: activations
            const int rg = f >> 1, kh = f & 1;
            int row = n0 + rg * 32 + lrow;
            if (row >= N_NODES) row = N_NODES - 1;   // dup row; epilogue skips OOB
            const ushort* arr = p ? xb_cur : agg;
            sp[q] = arr + (size_t)row * HIDDEN + kh * 16 + lhi * 8;
            adv[q] = 32;
        } else {                              // waves 2..7: weights
            const int fw = f - 8, j = fw >> 3, cbl = (fw >> 1) & 3, kh = fw & 1;
            const int g = j + 3 * p;
            sp[q] = wB[g] + ((size_t)(cb0 + cbl) * 32 + kh) * 512 + (size_t)lane * 8;
            adv[q] = 1024;
        }
    }

    // prologue: stage step 0 into buf 0 (8 issues, phase-major order)
    #pragma unroll
    for (int q = 0; q < 8; ++q) { gld16(sp[q], S + off[q]); sp[q] += adv[q]; }

    // one phase: retire this phase's 4 staged frags, read 10 operand frags, issue
    // next step's 4 stages, 12 MFMA. p=0: av x gi gates (sr,sz,in); p=1: xv x hh.
    #define PHASE(p, A0, A1, A2)  {                                                  \
        asm volatile("s_waitcnt vmcnt(4)\n\ts_barrier" ::: "memory");                \
        const ushort* P = S + (size_t)cur * 32768 + (p) * 32 * 512 + (size_t)lane * 8;\
        short8 v00 = *(const short8*)(P + (wr * 4 + 0) * 512);                       \
        short8 v01 = *(const short8*)(P + (wr * 4 + 1) * 512);                       \
        short8 v10 = *(const short8*)(P + (wr * 4 + 2) * 512);                       \
        short8 v11 = *(const short8*)(P + (wr * 4 + 3) * 512);                       \
        short8 W00 = *(const short8*)(P + (8 + 0 * 8 + wc * 2 + 0) * 512);           \
        short8 W01 = *(const short8*)(P + (8 + 0 * 8 + wc * 2 + 1) * 512);           \
        short8 W10 = *(const short8*)(P + (8 + 1 * 8 + wc * 2 + 0) * 512);           \
        short8 W11 = *(const short8*)(P + (8 + 1 * 8 + wc * 2 + 1) * 512);           \
        short8 W20 = *(const short8*)(P + (8 + 2 * 8 + wc * 2 + 0) * 512);           \
        short8 W21 = *(const short8*)(P + (8 + 2 * 8 + wc * 2 + 1) * 512);           \
        ushort* D = S + (size_t)(cur ^ 1) * 32768;                                   \
        gld16(sp[(p) * 4 + 0], D + off[(p) * 4 + 0]); sp[(p) * 4 + 0] += adv[(p) * 4 + 0]; \
        gld16(sp[(p) * 4 + 1], D + off[(p) * 4 + 1]); sp[(p) * 4 + 1] += adv[(p) * 4 + 1]; \
        gld16(sp[(p) * 4 + 2], D + off[(p) * 4 + 2]); sp[(p) * 4 + 2] += adv[(p) * 4 + 2]; \
        gld16(sp[(p) * 4 + 3], D + off[(p) * 4 + 3]); sp[(p) * 4 + 3] += adv[(p) * 4 + 3]; \
        __builtin_amdgcn_s_setprio(1);                                               \
        A0[0] = mfma32(v00, W00, A0[0]);  A0[1] = mfma32(v10, W00, A0[1]);           \
        A1[0] = mfma32(v00, W10, A1[0]);  A1[1] = mfma32(v10, W10, A1[1]);           \
        A2[0] = mfma32(v00, W20, A2[0]);  A2[1] = mfma32(v10, W20, A2[1]);           \
        A0[0] = mfma32(v01, W01, A0[0]);  A0[1] = mfma32(v11, W01, A0[1]);           \
        A1[0] = mfma32(v01, W11, A1[0]);  A1[1] = mfma32(v11, W11, A1[1]);           \
        A2[0] = mfma32(v01, W21, A2[0]);  A2[1] = mfma32(v11, W21, A2[1]);           \
        __builtin_amdgcn_s_setprio(0); }

    for (int ks = 0; ks < 16; ++ks) {
        const int cur = ks & 1;
        PHASE(0, a_sr, a_sz, a_in)   // av x gi(r,z,n)
        PHASE(1, a_sr, a_sz, a_hn)   // xv x hh(r,z,n)
    }
    #undef PHASE

    // epilogue: C/D map (32x32): col = lane&31, row = (reg&3) + 8*(reg>>2) + 4*(lane>>5)
    const int colL = (cb << 5) + lrow;
    const float bir = b_ih[colL] + b_hh[colL];
    const float biz = b_ih[HIDDEN + colL] + b_hh[HIDDEN + colL];
    const float bin = b_ih[2 * HIDDEN + colL];
    const float bhn = b_hh[2 * HIDDEN + colL];
    #pragma unroll
    for (int rf = 0; rf < 2; ++rf) {
        #pragma unroll
        for (int rg = 0; rg < 16; ++rg) {
            const int row = n0 + wr * 64 + rf * 32 + (rg & 3) + ((rg >> 2) << 3) + (lhi << 2);
            if (row >= N_NODES) continue;
            float vsr = a_sr[rf][rg] + bir;
            float vsz = a_sz[rf][rg] + biz;
            float vin = a_in[rf][rg] + bin;
            float vhn = a_hn[rf][rg] + bhn;
            float rr = 1.f / (1.f + __expf(-vsr));
            float zz = 1.f / (1.f + __expf(-vsz));
            float nn = tanhf(vin + rr * vhn);
            float h  = bf2f(xb_cur[(size_t)row * HIDDEN + colL]);
            float out = (1.f - zz) * nn + zz * h;
            if (F32OUT) outF[(size_t)row * HIDDEN + colL] = out;
            else        outB[(size_t)row * HIDDEN + colL] = f2bf(out);
        }
    }
}

extern "C" void kernel_launch(void* const* d_in, const int* in_sizes, int n_in,
                              void* d_out, int out_size, void* d_ws, size_t ws_size,
                              hipStream_t stream) {
    const int*   inputs = (const int*)d_in[0];
    const int*   A      = (const int*)d_in[1];
    const float* emb    = (const float*)d_in[2];
    const float* weight = (const float*)d_in[3];
    const float* w_ih   = (const float*)d_in[4];
    const float* w_hh   = (const float*)d_in[5];
    const float* b_ih   = (const float*)d_in[6];
    const float* b_hh   = (const float*)d_in[7];

    // ws: WihB 1.6 + Wb 1.05 + WFc 3.1 + WFhh 1.6 + bufA 51.2 + bufB 51.2 + sort 1.4 ≈ 111 MB
    // ax for layer 0 lives in d_out (51.2 of 102.4 MB); layer 1 ax reuses bufA.
    char* ws = (char*)d_ws;
    size_t off = 0;
    auto alloc = [&](size_t bytes) { void* p = ws + off; off += (bytes + 255) & ~255ull; return p; };
    ushort* WihB      = (ushort*)alloc((size_t)3 * HIDDEN * HIDDEN * sizeof(ushort));
    ushort* Wb        = (ushort*)alloc((size_t)2 * HIDDEN * HIDDEN * sizeof(ushort));
    ushort* WFc       = (ushort*)alloc((size_t)2 * 3 * HIDDEN * HIDDEN * sizeof(ushort));
    ushort* WFhh      = (ushort*)alloc((size_t)3 * HIDDEN * HIDDEN * sizeof(ushort));
    ushort* bufA      = (ushort*)alloc((size_t)N_NODES * HIDDEN * sizeof(ushort));
    ushort* bufB      = (ushort*)alloc((size_t)N_NODES * HIDDEN * sizeof(ushort));
    int*    count     = (int*)alloc((size_t)N_NODES * sizeof(int));
    int*    row_start = (int*)alloc((size_t)(N_NODES + 1) * sizeof(int));
    int*    cursor    = (int*)alloc((size_t)N_NODES * sizeof(int));
    int*    esrc      = (int*)alloc((size_t)N_EDGES * sizeof(int));
    ushort* ax0       = (ushort*)d_out;

    const int nW3 = 3 * HIDDEN * HIDDEN, nW2 = 2 * HIDDEN * HIDDEN;
    const size_t WF_L = (size_t)3 * HIDDEN * HIDDEN;   // per-layer packed-weight stride

    k_cvt8<<<(nW3 / 8 + 255) / 256, 256, 0, stream>>>(w_ih, WihB, nW3);
    k_cvt8<<<(nW2 / 8 + 255) / 256, 256, 0, stream>>>(weight, Wb, nW2);
    k_pack_hh<<<(nW3 / 8 + 255) / 256, 256, 0, stream>>>(w_hh, WFhh);
    k_gemm_w<<<dim3(12, 4, 2), 256, 0, stream>>>(WihB, Wb, WFc);   // frag-major Wc

    k_gather<<<(N_NODES * 64 + 255) / 256, 256, 0, stream>>>(inputs, emb, bufA);

    hipMemsetAsync(count, 0, (size_t)N_NODES * sizeof(int), stream);
    k_hist<<<(N_EDGES + 255) / 256, 256, 0, stream>>>(inputs, A, count);
    k_scan<<<1, SCAN_T, 0, stream>>>(count, row_start, cursor);
    k_place<<<(N_EDGES + 255) / 256, 256, 0, stream>>>(inputs, A, cursor, esrc);

    dim3 gGru(8 * 4 * ((NBX + 7) / 8));   // x(=XCD) * by(4) * row-groups
    dim3 ga((N_NODES + 3) / 4);

    // Layer 0: ax0 = segsum(x0) -> d_out region; GRU(ax0, x0=bufA) -> bufB
    k_agg<<<ga, 256, 0, stream>>>(row_start, esrc, bufA, ax0);
    k_gru9<false><<<gGru, 512, 0, stream>>>(ax0, bufA, WFc, WFhh, b_ih, b_hh, bufB, nullptr);

    // Layer 1: ax1 = segsum(x1) -> bufA (x0 dead); GRU(ax1, x1=bufB) -> f32 d_out
    k_agg<<<ga, 256, 0, stream>>>(row_start, esrc, bufB, bufA);
    k_gru9<true><<<gGru, 512, 0, stream>>>(bufA, bufB, WFc + WF_L, WFhh, b_ih, b_hh,
                                           nullptr, (float*)d_out);
}

// Round 9
// 875.711 us; speedup vs baseline: 1.3453x; 1.0219x over previous
//
#include <hip/hip_runtime.h>
#include <stdint.h>

#define N_NODES 50000
#define HIDDEN  512
#define N_EDGES 200000

#define BK 32
#define LDP 40   // padded LDS row stride (k_gemm_w only)
#define NBX ((N_NODES + 127) / 128)

typedef __attribute__((ext_vector_type(8)))  short short8;
typedef __attribute__((ext_vector_type(4)))  float floatx4;
typedef __attribute__((ext_vector_type(16))) float floatx16;

__device__ inline float bf2f(ushort u) {
    union { uint32_t u; float f; } v; v.u = ((uint32_t)u) << 16; return v.f;
}
__device__ inline ushort f2bf(float f) {
    union { float f; uint32_t u; } v; v.f = f;
    uint32_t r = v.u + 0x7fffu + ((v.u >> 16) & 1u);   // round-to-nearest-even
    return (ushort)(r >> 16);
}
__device__ inline floatx4 mfma16(short8 a, short8 b, floatx4 c) {
    return __builtin_amdgcn_mfma_f32_16x16x32_bf16(a, b, c, 0, 0, 0);
}
__device__ inline floatx16 mfma32(short8 a, short8 b, floatx16 c) {
    return __builtin_amdgcn_mfma_f32_32x32x16_bf16(a, b, c, 0, 0, 0);
}
// async global->LDS, 16B per lane; lds dest is wave-uniform base + lane*16,
// global src address is PER-LANE (pre-swizzled gather is legal).
__device__ inline void gld16(const void* g, void* l) {
    __builtin_amdgcn_global_load_lds(
        (const __attribute__((address_space(1))) unsigned int*)g,
        (__attribute__((address_space(3))) unsigned int*)l, 16, 0, 0);
}
// inline-asm LDS read: INVISIBLE to the compiler's waitcnt insertion, so the
// gld16 DMA stream is never force-drained by a compiler vmcnt(0) before LDS reads
// (v8/v9 post-mortem: that conservative drain was ~60% of every phase). Pairing
// rule: explicit lgkmcnt(0) + sched_barrier(0) before first use (rule #18).
template<int OFF>
__device__ inline short8 dsr(uint a) {
    short8 r;
    asm volatile("ds_read_b128 %0, %1 offset:%2" : "=v"(r) : "v"(a), "n"(OFF));
    return r;
}
// inputs is arange(N_NODES); if harness kept int64, the int32 view is [0,0,1,0,2,0,...]
__device__ inline bool idx_is64(const int* __restrict__ inputs) {
    return inputs[1] == 0 && inputs[2] == 1;
}

// x = bf16(emb[inputs]) : 8 f32 -> 8 bf16 per thread
__global__ void k_gather(const int* __restrict__ inputs, const float* __restrict__ emb,
                         ushort* __restrict__ xb) {
    bool is64 = idx_is64(inputs);
    int t = blockIdx.x * blockDim.x + threadIdx.x;   // N_NODES*64 threads
    int row = t >> 6, s8 = (t & 63) << 3;
    if (row >= N_NODES) return;
    int srow = is64 ? inputs[2 * row] : inputs[row];
    srow = srow < 0 ? 0 : (srow >= N_NODES ? N_NODES - 1 : srow);
    const float* src = emb + (size_t)srow * HIDDEN + s8;
    float4 v0 = *(const float4*)(src);
    float4 v1 = *(const float4*)(src + 4);
    ushort o[8] = { f2bf(v0.x), f2bf(v0.y), f2bf(v0.z), f2bf(v0.w),
                    f2bf(v1.x), f2bf(v1.y), f2bf(v1.z), f2bf(v1.w) };
    *(uint4*)(xb + (size_t)row * HIDDEN + s8) = *(uint4*)o;
}

// generic f32 -> bf16 (8/thread), row-major preserved
__global__ void k_cvt8(const float* __restrict__ src, ushort* __restrict__ dst, int n) {
    int t = blockIdx.x * blockDim.x + threadIdx.x;
    int base = t * 8;
    if (base >= n) return;
    float4 v0 = *(const float4*)(src + base);
    float4 v1 = *(const float4*)(src + base + 4);
    ushort o[8] = { f2bf(v0.x), f2bf(v0.y), f2bf(v0.z), f2bf(v0.w),
                    f2bf(v1.x), f2bf(v1.y), f2bf(v1.z), f2bf(v1.w) };
    *(uint4*)(dst + base) = *(uint4*)o;
}

// Fragment-major weight layout for mfma_32x32x16_bf16 B operand:
// element (grow in [0,1536), k in [0,512)):
//   g = grow>>9, col = grow&511, cb = col>>5, lanelo = col&31,
//   kk = k>>4, hi = (k>>3)&1, j = k&7, lane = lanelo + hi*32
//   idx = (((g*16 + cb)*32 + kk)*64 + lane)*8 + j
// -> each (g,cb,kk) frag is a contiguous 1KB panel; wave load = base + lane*16.
__device__ inline size_t wf_index(int grow, int k) {
    int g3 = grow >> 9, gcol = grow & 511;
    int cb = gcol >> 5, llo = gcol & 31;
    int kk = k >> 4, hi = (k >> 3) & 1, jj = k & 7;
    return ((((size_t)g3 * 16 + cb) * 32 + kk) * 64 + llo + hi * 32) * 8 + jj;
}

// Wc[l][g][k] = sum_j wih[g][j] * W[l][k][j]  (combined gi weights), written frag-major.
// A = WihB [1536][512] contig-j ; B = Wb[l] [512][512] contig-j ; M=1536,N=512,K=512.
__global__ __launch_bounds__(256) void k_gemm_w(const ushort* __restrict__ Aw,
                                                const ushort* __restrict__ Bw,
                                                ushort* __restrict__ Cw) {
    __shared__ ushort As[128][LDP];
    __shared__ ushort Bs[128][LDP];
    const int l = blockIdx.z;
    const ushort* Bp = Bw + (size_t)l * HIDDEN * HIDDEN;
    ushort* Cp = Cw + (size_t)l * 3 * HIDDEN * HIDDEN;
    const int n0 = blockIdx.x * 128, c0 = blockIdx.y * 128;
    const int t = threadIdx.x;
    const int wave = t >> 6, lane = t & 63;
    const int wm = (wave >> 1) << 6, wn = (wave & 1) << 6;
    const int fr = lane & 15, fk = (lane >> 4) << 3;
    const int lm = t >> 2, lk = (t & 3) << 3;
    floatx4 acc[4][4] = {};

    for (int k0 = 0; k0 < HIDDEN; k0 += BK) {
        *(uint4*)&As[lm][lk]      = *(const uint4*)(Aw + (size_t)(n0 + lm) * HIDDEN + k0 + lk);
        *(uint4*)&As[64 + lm][lk] = *(const uint4*)(Aw + (size_t)(n0 + 64 + lm) * HIDDEN + k0 + lk);
        *(uint4*)&Bs[lm][lk]      = *(const uint4*)(Bp + (size_t)(c0 + lm) * HIDDEN + k0 + lk);
        *(uint4*)&Bs[64 + lm][lk] = *(const uint4*)(Bp + (size_t)(c0 + 64 + lm) * HIDDEN + k0 + lk);
        __syncthreads();
        short8 aa[4], bb[4];
        #pragma unroll
        for (int i = 0; i < 4; ++i) {
            aa[i] = *(const short8*)&As[wm + i * 16 + fr][fk];
            bb[i] = *(const short8*)&Bs[wn + i * 16 + fr][fk];
        }
        #pragma unroll
        for (int i = 0; i < 4; ++i)
            #pragma unroll
            for (int j = 0; j < 4; ++j)
                acc[i][j] = mfma16(aa[i], bb[j], acc[i][j]);
        __syncthreads();
    }
    const int er = (lane >> 4) << 2, ec = lane & 15;
    #pragma unroll
    for (int i = 0; i < 4; ++i)
        #pragma unroll
        for (int j = 0; j < 4; ++j)
            #pragma unroll
            for (int r = 0; r < 4; ++r) {
                int grow = n0 + wm + i * 16 + er + r;   // gi-output row (gate dim)
                int kcol = c0 + wn + j * 16 + ec;       // k dim
                Cp[wf_index(grow, kcol)] = f2bf(acc[i][j][r]);
            }
}

// pack w_hh (f32 [1536][512]) into fragment-major bf16
__global__ void k_pack_hh(const float* __restrict__ whh, ushort* __restrict__ wfh) {
    int t = blockIdx.x * blockDim.x + threadIdx.x;   // 1536*64 threads
    if (t >= 3 * HIDDEN * HIDDEN / 8) return;
    int grow = t >> 6, k = (t & 63) << 3;
    const float* src = whh + (size_t)grow * HIDDEN + k;
    ushort o[8];
    #pragma unroll
    for (int j = 0; j < 8; ++j) o[j] = f2bf(src[j]);
    *(uint4*)(wfh + wf_index(grow, k)) = *(uint4*)o;   // j=0..7 contiguous -> 16B store
}

// ---- counting sort of edges by dst (once per call; graph shared by both layers) ----
__global__ void k_hist(const int* __restrict__ inputs, const int* __restrict__ A,
                       int* __restrict__ count) {
    bool is64 = idx_is64(inputs);
    int e = blockIdx.x * blockDim.x + threadIdx.x;
    if (e >= N_EDGES) return;
    int d = is64 ? A[2 * (N_EDGES + e)] : A[N_EDGES + e];
    if (d < 0 || d >= N_NODES) return;
    atomicAdd(count + d, 1);
}

#define SCAN_T 1024
__global__ __launch_bounds__(SCAN_T) void k_scan(const int* __restrict__ count,
                                                 int* __restrict__ row_start,
                                                 int* __restrict__ cursor) {
    __shared__ int part[SCAN_T];
    const int t = threadIdx.x;
    const int chunk = (N_NODES + SCAN_T - 1) / SCAN_T;   // 49
    const int base = t * chunk;
    int s = 0;
    for (int i = 0; i < chunk; ++i) {
        int idx = base + i;
        if (idx < N_NODES) s += count[idx];
    }
    part[t] = s;
    __syncthreads();
    for (int off = 1; off < SCAN_T; off <<= 1) {
        int add = (t >= off) ? part[t - off] : 0;
        __syncthreads();
        part[t] += add;
        __syncthreads();
    }
    int running = (t == 0) ? 0 : part[t - 1];
    for (int i = 0; i < chunk; ++i) {
        int idx = base + i;
        if (idx < N_NODES) {
            row_start[idx] = running;
            cursor[idx] = running;
            running += count[idx];
        }
    }
    if (t == 0) row_start[N_NODES] = part[SCAN_T - 1];
}

__global__ void k_place(const int* __restrict__ inputs, const int* __restrict__ A,
                        int* __restrict__ cursor, int* __restrict__ esrc) {
    bool is64 = idx_is64(inputs);
    int e = blockIdx.x * blockDim.x + threadIdx.x;
    if (e >= N_EDGES) return;
    int s, d;
    if (is64) { s = A[2 * e]; d = A[2 * (N_EDGES + e)]; }
    else      { s = A[e];     d = A[N_EDGES + e]; }
    if (s < 0 || s >= N_NODES || d < 0 || d >= N_NODES) return;
    int pos = atomicAdd(cursor + d, 1);
    esrc[pos] = s;
}

// ax[n] = sum_{e: dst=n} x[src[e]] : one wave per node, lane owns 8 cols, f32 acc -> bf16
__global__ __launch_bounds__(256) void k_agg(const int* __restrict__ row_start,
                                             const int* __restrict__ esrc,
                                             const ushort* __restrict__ x,
                                             ushort* __restrict__ ax) {
    int node = blockIdx.x * 4 + (threadIdx.x >> 6);
    if (node >= N_NODES) return;
    int lane = threadIdx.x & 63;
    int q = lane << 3;
    int beg = row_start[node], end = row_start[node + 1];
    float acc[8] = {};
    for (int i = beg; i < end; ++i) {
        int s = esrc[i];
        uint4 v = *(const uint4*)(x + (size_t)s * HIDDEN + q);
        const ushort* u = (const ushort*)&v;
        #pragma unroll
        for (int j = 0; j < 8; ++j) acc[j] += bf2f(u[j]);
    }
    ushort o[8];
    #pragma unroll
    for (int j = 0; j < 8; ++j) o[j] = f2bf(acc[j]);
    *(uint4*)(ax + (size_t)node * HIDDEN + q) = *(uint4*)o;
}

// Fused GRU v10 = v9 data path + asm-ds_read phases (m201/HK read discipline).
// v9 post-mortem: phase time scaled with content (v8 1556 -> v9 3000 cyc), pointing
// at compiler-inserted conservative s_waitcnt vmcnt(0) before the C-level LDS reads
// that follow global_load_lds (may-alias ordering) -- which force-drains the DMA
// pipeline every phase, reducing the staging lead to ~1 phase. Fix: issue the 10
// operand reads as inline-asm ds_read_b128 (opaque to the compiler's waitcnt pass),
// then gld16 x4, then the ONLY waits in the loop: counted vmcnt(4)+s_barrier
// (validity of NEXT phase's slots, staged a full step ago) and lgkmcnt(0)+
// sched_barrier(0) (rule #18) before the MFMA cluster.
// Geometry/descriptors identical to v9: 512 thr = 8 waves (2 row x 4 col), BM=128,
// BN=128, K-step=32, 2 phases/step, buffer = 64 slots x 1KB, 128 KB LDS total.
// vmcnt invariant: 8 outstanding at each vmcnt; oldest 4 are exactly the next
// phase's slots (verified by induction from the prologue).
template<bool F32OUT>
__global__ __launch_bounds__(512, 2) void k_gru10(
    const ushort* __restrict__ agg, const ushort* __restrict__ xb_cur,
    const ushort* __restrict__ wfc,   // this layer's packed gi weights [3][16][32][64][8]
    const ushort* __restrict__ wfh,   // packed w_hh                  [3][16][32][64][8]
    const float* __restrict__ b_ih, const float* __restrict__ b_hh,
    ushort* __restrict__ outB, float* __restrict__ outF)
{
    __shared__ ushort S[2 * 32768];          // [buf][phase 0..1][slot 0..31][512], 128 KB
    const int x  = blockIdx.x & 7;           // XCD slot
    const int n  = blockIdx.x >> 3;
    const int by = n & 3;                    // col-block (128 cols)
    const int bx = x + ((n >> 2) << 3);      // row-block; 4 col-slices consecutive/XCD
    if (bx >= NBX) return;
    const int n0 = bx * 128;
    const int t = threadIdx.x, w = t >> 6, lane = t & 63;
    const int lrow = lane & 31, lhi = lane >> 5;
    const int wr = w >> 2, wc = w & 3;       // row-half 0/1, col-group 0..3
    const int cb0 = by * 4;
    const int cb = cb0 + wc;                 // this wave's 32-col block in [0,16)

    floatx16 a_sr[2] = {}, a_sz[2] = {}, a_in[2] = {}, a_hn[2] = {};

    const ushort* wB[6] = { wfc, wfc + 262144, wfc + 524288,    // gi r,z,n
                            wfh, wfh + 262144, wfh + 524288 };  // hh r,z,n

    // ---- staging descriptors: wave w stages frags f = 4w..4w+3 of each phase ----
    // slot(p, f) = p*32 + f. f<8: act (A for p=0, X for p=1), rg = f>>1, kh = f&1;
    // f>=8: fw=f-8: weight panel g = (fw>>3) + 3p, col-group cbl = (fw>>1)&3, kh = fw&1.
    const ushort* sp[8];   // per-lane global source, q = p*4 + e
    int           adv[8];  // ushort advance per K32 step
    int           off[8];  // LDS ushort offset within a buffer
    #pragma unroll
    for (int q = 0; q < 8; ++q) {
        const int p = q >> 2, e = q & 3;
        const int f = 4 * w + e;             // frag index in [0,32)
        off[q] = (p * 32 + f) * 512;
        if (f < 8) {                          // waves 0,1: activations
            const int rg = f >> 1, kh = f & 1;
            int row = n0 + rg * 32 + lrow;
            if (row >= N_NODES) row = N_NODES - 1;   // dup row; epilogue skips OOB
            const ushort* arr = p ? xb_cur : agg;
            sp[q] = arr + (size_t)row * HIDDEN + kh * 16 + lhi * 8;
            adv[q] = 32;
        } else {                              // waves 2..7: weights
            const int fw = f - 8, j = fw >> 3, cbl = (fw >> 1) & 3, kh = fw & 1;
            const int g = j + 3 * p;
            sp[q] = wB[g] + ((size_t)(cb0 + cbl) * 32 + kh) * 512 + (size_t)lane * 8;
            adv[q] = 1024;
        }
    }

    // LDS byte-offset bases for the asm reads (S is the only __shared__ array).
    const uint ldsBase = (uint)(uintptr_t)(__attribute__((address_space(3))) ushort*)S;
    const uint laneOff = (uint)lane * 16u;
    const uint wrOff   = (uint)wr * 4096u;    // wr*4 slots x 1KB
    const uint wcOff   = (uint)wc * 2048u;    // wc*2 slots x 1KB

    // prologue: stage step 0 into buf 0 (phase-major), then establish ph0 validity.
    #pragma unroll
    for (int q = 0; q < 8; ++q) { gld16(sp[q], S + off[q]); sp[q] += adv[q]; }
    asm volatile("s_waitcnt vmcnt(4)\n\ts_barrier" ::: "memory");

    // one phase: 10 asm ds_reads (phase p operands; valid from prev phase's barrier),
    // 4 gld16 (phase-p slots of next buffer), counted vmcnt+barrier (publishes phase
    // p+1 validity), lgkmcnt(0)+sched_barrier, 12 MFMA under setprio.
    #define PHASE(p, A0, A1, A2)  {                                                  \
        const uint base = ldsBase + laneOff + (uint)cur * 65536u + (p) * 32768u;     \
        const uint ab = base + wrOff;                                                \
        const uint wbo = base + 8192u + wcOff;                                       \
        short8 v00 = dsr<0>(ab);                                                     \
        short8 v01 = dsr<1024>(ab);                                                  \
        short8 v10 = dsr<2048>(ab);                                                  \
        short8 v11 = dsr<3072>(ab);                                                  \
        short8 W00 = dsr<0>(wbo);                                                    \
        short8 W01 = dsr<1024>(wbo);                                                 \
        short8 W10 = dsr<8192>(wbo);                                                 \
        short8 W11 = dsr<9216>(wbo);                                                 \
        short8 W20 = dsr<16384>(wbo);                                                \
        short8 W21 = dsr<17408>(wbo);                                                \
        ushort* D = S + (size_t)(cur ^ 1) * 32768;                                   \
        gld16(sp[(p) * 4 + 0], D + off[(p) * 4 + 0]); sp[(p) * 4 + 0] += adv[(p) * 4 + 0]; \
        gld16(sp[(p) * 4 + 1], D + off[(p) * 4 + 1]); sp[(p) * 4 + 1] += adv[(p) * 4 + 1]; \
        gld16(sp[(p) * 4 + 2], D + off[(p) * 4 + 2]); sp[(p) * 4 + 2] += adv[(p) * 4 + 2]; \
        gld16(sp[(p) * 4 + 3], D + off[(p) * 4 + 3]); sp[(p) * 4 + 3] += adv[(p) * 4 + 3]; \
        asm volatile("s_waitcnt vmcnt(4)\n\ts_barrier" ::: "memory");                \
        asm volatile("s_waitcnt lgkmcnt(0)" ::: "memory");                           \
        __builtin_amdgcn_sched_barrier(0);                                           \
        __builtin_amdgcn_s_setprio(1);                                               \
        A0[0] = mfma32(v00, W00, A0[0]);  A0[1] = mfma32(v10, W00, A0[1]);           \
        A1[0] = mfma32(v00, W10, A1[0]);  A1[1] = mfma32(v10, W10, A1[1]);           \
        A2[0] = mfma32(v00, W20, A2[0]);  A2[1] = mfma32(v10, W20, A2[1]);           \
        A0[0] = mfma32(v01, W01, A0[0]);  A0[1] = mfma32(v11, W01, A0[1]);           \
        A1[0] = mfma32(v01, W11, A1[0]);  A1[1] = mfma32(v11, W11, A1[1]);           \
        A2[0] = mfma32(v01, W21, A2[0]);  A2[1] = mfma32(v11, W21, A2[1]);           \
        __builtin_amdgcn_s_setprio(0); }

    for (int ks = 0; ks < 16; ++ks) {
        const int cur = ks & 1;
        PHASE(0, a_sr, a_sz, a_in)   // av x gi(r,z,n)
        PHASE(1, a_sr, a_sz, a_hn)   // xv x hh(r,z,n)
    }
    #undef PHASE

    // epilogue: C/D map (32x32): col = lane&31, row = (reg&3) + 8*(reg>>2) + 4*(lane>>5)
    const int colL = (cb << 5) + lrow;
    const float bir = b_ih[colL] + b_hh[colL];
    const float biz = b_ih[HIDDEN + colL] + b_hh[HIDDEN + colL];
    const float bin = b_ih[2 * HIDDEN + colL];
    const float bhn = b_hh[2 * HIDDEN + colL];
    #pragma unroll
    for (int rf = 0; rf < 2; ++rf) {
        #pragma unroll
        for (int rg = 0; rg < 16; ++rg) {
            const int row = n0 + wr * 64 + rf * 32 + (rg & 3) + ((rg >> 2) << 3) + (lhi << 2);
            if (row >= N_NODES) continue;
            float vsr = a_sr[rf][rg] + bir;
            float vsz = a_sz[rf][rg] + biz;
            float vin = a_in[rf][rg] + bin;
            float vhn = a_hn[rf][rg] + bhn;
            float rr = 1.f / (1.f + __expf(-vsr));
            float zz = 1.f / (1.f + __expf(-vsz));
            float nn = tanhf(vin + rr * vhn);
            float h  = bf2f(xb_cur[(size_t)row * HIDDEN + colL]);
            float out = (1.f - zz) * nn + zz * h;
            if (F32OUT) outF[(size_t)row * HIDDEN + colL] = out;
            else        outB[(size_t)row * HIDDEN + colL] = f2bf(out);
        }
    }
}

extern "C" void kernel_launch(void* const* d_in, const int* in_sizes, int n_in,
                              void* d_out, int out_size, void* d_ws, size_t ws_size,
                              hipStream_t stream) {
    const int*   inputs = (const int*)d_in[0];
    const int*   A      = (const int*)d_in[1];
    const float* emb    = (const float*)d_in[2];
    const float* weight = (const float*)d_in[3];
    const float* w_ih   = (const float*)d_in[4];
    const float* w_hh   = (const float*)d_in[5];
    const float* b_ih   = (const float*)d_in[6];
    const float* b_hh   = (const float*)d_in[7];

    // ws: WihB 1.6 + Wb 1.05 + WFc 3.1 + WFhh 1.6 + bufA 51.2 + bufB 51.2 + sort 1.4 ≈ 111 MB
    // ax for layer 0 lives in d_out (51.2 of 102.4 MB); layer 1 ax reuses bufA.
    char* ws = (char*)d_ws;
    size_t off = 0;
    auto alloc = [&](size_t bytes) { void* p = ws + off; off += (bytes + 255) & ~255ull; return p; };
    ushort* WihB      = (ushort*)alloc((size_t)3 * HIDDEN * HIDDEN * sizeof(ushort));
    ushort* Wb        = (ushort*)alloc((size_t)2 * HIDDEN * HIDDEN * sizeof(ushort));
    ushort* WFc       = (ushort*)alloc((size_t)2 * 3 * HIDDEN * HIDDEN * sizeof(ushort));
    ushort* WFhh      = (ushort*)alloc((size_t)3 * HIDDEN * HIDDEN * sizeof(ushort));
    ushort* bufA      = (ushort*)alloc((size_t)N_NODES * HIDDEN * sizeof(ushort));
    ushort* bufB      = (ushort*)alloc((size_t)N_NODES * HIDDEN * sizeof(ushort));
    int*    count     = (int*)alloc((size_t)N_NODES * sizeof(int));
    int*    row_start = (int*)alloc((size_t)(N_NODES + 1) * sizeof(int));
    int*    cursor    = (int*)alloc((size_t)N_NODES * sizeof(int));
    int*    esrc      = (int*)alloc((size_t)N_EDGES * sizeof(int));
    ushort* ax0       = (ushort*)d_out;

    const int nW3 = 3 * HIDDEN * HIDDEN, nW2 = 2 * HIDDEN * HIDDEN;
    const size_t WF_L = (size_t)3 * HIDDEN * HIDDEN;   // per-layer packed-weight stride

    k_cvt8<<<(nW3 / 8 + 255) / 256, 256, 0, stream>>>(w_ih, WihB, nW3);
    k_cvt8<<<(nW2 / 8 + 255) / 256, 256, 0, stream>>>(weight, Wb, nW2);
    k_pack_hh<<<(nW3 / 8 + 255) / 256, 256, 0, stream>>>(w_hh, WFhh);
    k_gemm_w<<<dim3(12, 4, 2), 256, 0, stream>>>(WihB, Wb, WFc);   // frag-major Wc

    k_gather<<<(N_NODES * 64 + 255) / 256, 256, 0, stream>>>(inputs, emb, bufA);

    hipMemsetAsync(count, 0, (size_t)N_NODES * sizeof(int), stream);
    k_hist<<<(N_EDGES + 255) / 256, 256, 0, stream>>>(inputs, A, count);
    k_scan<<<1, SCAN_T, 0, stream>>>(count, row_start, cursor);
    k_place<<<(N_EDGES + 255) / 256, 256, 0, stream>>>(inputs, A, cursor, esrc);

    dim3 gGru(8 * 4 * ((NBX + 7) / 8));   // x(=XCD) * by(4) * row-groups
    dim3 ga((N_NODES + 3) / 4);

    // Layer 0: ax0 = segsum(x0) -> d_out region; GRU(ax0, x0=bufA) -> bufB
    k_agg<<<ga, 256, 0, stream>>>(row_start, esrc, bufA, ax0);
    k_gru10<false><<<gGru, 512, 0, stream>>>(ax0, bufA, WFc, WFhh, b_ih, b_hh, bufB, nullptr);

    // Layer 1: ax1 = segsum(x1) -> bufA (x0 dead); GRU(ax1, x1=bufB) -> f32 d_out
    k_agg<<<ga, 256, 0, stream>>>(row_start, esrc, bufB, bufA);
    k_gru10<true><<<gGru, 512, 0, stream>>>(bufA, bufB, WFc + WF_L, WFhh, b_ih, b_hh,
                                            nullptr, (float*)d_out);
}